// Round 3
// baseline (298.611 us; speedup 1.0000x reference)
//
#include <hip/hip_runtime.h>
#include <hip/hip_bf16.h>
#include <stdint.h>
#include <stddef.h>

// SimpleStateSpaceModel: B=4, S=4096, D=1024. FP32 in/out; bf16 MFMA inside.
// Pipeline (106 MB of d_ws):
//   C0 cast_all         : x->xb (32MB), {dt_w,B_w,C_w}->wcat (6MB)
//   K1 gemm8<bf16>      : P[m,0:1024]=x@dt_w^T, P[m,1024:2048]=x@B_w^T
//   S1 scan_local       : g,u from (P,xb); in-place P <- [hl(t) | pg(t)]
//   S2 scan_carry       : sequential combine over 128 chunks
//   S3 scan_fix         : h(t) = hl(t) + carry*pg(t)
//   K6 gemm8<f32>       : out = h@C_w^T + D*x (xb epilogue)
// R3: GEMM phase skeleton re-ported to the m201 form: ds_reads issue BEFORE
// the phase barrier (overlap barrier skew + previous MFMA drain); MFMA region
// is pure {lgkmcnt(0); sched_barrier; setprio; 16 MFMA}; counted vmcnt(4)
// guards moved to the post-MFMA slot of the PREVIOUS phase (ph4/ph1/ph2),
// so staging waits hide under compute. Scan/cast unchanged from R2.

#define Bdim 4
#define Sdim 4096
#define Dd   1024
#define Mdim (Bdim * Sdim)      // 16384
#define CCH  128                // scan chunks per sequence
#define LCH  (Sdim / CCH)       // 32 steps per chunk

typedef __attribute__((ext_vector_type(8))) short  short8;
typedef __attribute__((ext_vector_type(4))) short  short4v;
typedef __attribute__((ext_vector_type(4))) float  floatx4;

#if __has_builtin(__builtin_amdgcn_exp2f)
#define EXP2(x) __builtin_amdgcn_exp2f(x)
#else
#define EXP2(x) exp2f(x)
#endif
#if __has_builtin(__builtin_amdgcn_logf)
#define LOG2(x) __builtin_amdgcn_logf(x)
#else
#define LOG2(x) __log2f(x)
#endif
#define LOG2E 1.44269504088896f
#define LN2   0.69314718055995f

__device__ __forceinline__ float b2f(short v) {
  unsigned u = ((unsigned)(unsigned short)v) << 16;
  float f; __builtin_memcpy(&f, &u, 4); return f;
}
// HW RNE bf16 convert
__device__ __forceinline__ short f2b(float f) {
  __hip_bfloat16 h = __float2bfloat16(f);
  short s; __builtin_memcpy(&s, &h, 2); return s;
}

__device__ __forceinline__ short8 ld8f(const float* p) {
  floatx4 lo = *(const floatx4*)p;
  floatx4 hi = *(const floatx4*)(p + 4);
  short8 r;
  r[0] = f2b(lo[0]); r[1] = f2b(lo[1]); r[2] = f2b(lo[2]); r[3] = f2b(lo[3]);
  r[4] = f2b(hi[0]); r[5] = f2b(hi[1]); r[6] = f2b(hi[2]); r[7] = f2b(hi[3]);
  return r;
}

__device__ __forceinline__ void st_out(short* p, float v) { *p = f2b(v); }
__device__ __forceinline__ void st_out(float* p, float v) { *p = v; }

// async 16B global->LDS (DMA). lds dest wave-uniform; lane i -> l + i*16. [m97]
__device__ __forceinline__ void cp16(const void* g, void* l) {
  __builtin_amdgcn_global_load_lds(
      (__attribute__((address_space(1))) void*)g,
      (__attribute__((address_space(3))) void*)l, 16, 0, 0);
}

// ---------------------------------------------------------------------------
// gemm8: Out[m,n] = sum_k A[m,k]*W[n,k], A/W bf16.
// 256x256 tile, BK=64, 8 waves (2M x 4N), per-wave 128x64 output.
// m201-skeleton phases: {ds_read frags; stage; barrier; lgkmcnt(0);
// sched_barrier; setprio(1); 16 MFMA; setprio(0); [vmcnt(4)]; barrier}.
// Staging (tile t+1, other buffer): ph1 A-h0, ph2 B-h0, ph3 B-h1, ph4 A-h1.
// Guards (pre-B2): ph4 vmcnt(4) -> next ph1's A0,B0; ph1 vmcnt(4) -> ph2's
// B1; ph2 vmcnt(4) -> ph3's A1. Never 0 except the last-tile 2-load drain.
// ---------------------------------------------------------------------------
#define STGA(bufB, h, kk) do { \
  cp16(Ag + (size_t)((h) * 64) * lda + (kk), \
       smc + (bufB) + ((h) * 64 + ldsArow) * 128); \
  cp16(Ag + (size_t)((h) * 64 + 128) * lda + (kk), \
       smc + (bufB) + ((h) * 64 + 128 + ldsArow) * 128); \
} while (0)

#define STGB(bufB, h, kk) do { \
  cp16(Bg + (size_t)((h) * 32) * ldw + (kk), \
       smc + (bufB) + ((h) * 32 + ldsBrow) * 128); \
  cp16(Bg + (size_t)((h) * 32 + 128) * ldw + (kk), \
       smc + (bufB) + ((h) * 32 + 128 + ldsBrow) * 128); \
} while (0)

#define LDA4(bufB, mh) do { \
  _Pragma("unroll") \
  for (int mf = 0; mf < 4; ++mf) { \
    const char* p_ = smc + (bufB) + (wm + (mh) * 64 + mf * 16 + l16) * 128; \
    a[mf][0] = *(const short8*)(p_ + c0x); \
    a[mf][1] = *(const short8*)(p_ + c1x); \
  } \
} while (0)

#define LDB2(bufB, nh, bb) do { \
  _Pragma("unroll") \
  for (int g = 0; g < 2; ++g) { \
    const char* p_ = smc + (bufB) + (wn + (nh) * 32 + g * 16 + l16) * 128; \
    bb[g][0] = *(const short8*)(p_ + c0x); \
    bb[g][1] = *(const short8*)(p_ + c1x); \
  } \
} while (0)

// pure MFMA cluster (one C-quadrant over K=64), setprio wrapped (T5)
#define MM8(mh, nh, bb) do { \
  __builtin_amdgcn_s_setprio(1); \
  _Pragma("unroll") \
  for (int mf = 0; mf < 4; ++mf) { \
    _Pragma("unroll") \
    for (int g = 0; g < 2; ++g) { \
      floatx4 c_ = acc[(mh) * 4 + mf][(nh) * 2 + g]; \
      c_ = __builtin_amdgcn_mfma_f32_16x16x32_bf16(a[mf][0], bb[g][0], c_, 0, 0, 0); \
      c_ = __builtin_amdgcn_mfma_f32_16x16x32_bf16(a[mf][1], bb[g][1], c_, 0, 0, 0); \
      acc[(mh) * 4 + mf][(nh) * 2 + g] = c_; \
    } \
  } \
  __builtin_amdgcn_s_setprio(0); \
} while (0)

#define BARR   asm volatile("s_barrier" ::: "memory")
#define LGKM0  asm volatile("s_waitcnt lgkmcnt(0)" ::: "memory")
#define VMC(n) asm volatile("s_waitcnt vmcnt(" #n ")" ::: "memory")
#define SCHED0 __builtin_amdgcn_sched_barrier(0)

template <typename OT, bool FUSE>
__global__ __launch_bounds__(512, 2) void gemm8(
    const short* __restrict__ A, int lda,
    const short* __restrict__ W, int ldw,    // bf16 [N][K] row-major
    OT* __restrict__ Out, int ldo, int K,
    const float* __restrict__ Dp, const short* __restrict__ Xr, int ldx)
{
  __shared__ short smem[65536];   // 128 KiB: Abuf0|Abuf1|Bbuf0|Bbuf1, 32K each
  char* smc = (char*)smem;

  const int tid  = threadIdx.x;
  const int lane = tid & 63, wv = tid >> 6;
  const int quad = lane >> 4, l16 = lane & 15;
  const int wm = (wv & 1) << 7;           // 0 / 128
  const int wn = (wv >> 1) << 6;          // 0,64,128,192
  const int m0 = blockIdx.x << 8;
  const int n0 = blockIdx.y << 8;

  // read-side swizzle: phys col-byte = logical ^ ((row&7)<<4); row&7 == l16&7
  const int sx  = (l16 & 7) << 4;
  const int c0x = (quad << 4) ^ sx;            // ks=0 fragment column
  const int c1x = (64 + (quad << 4)) ^ sx;     // ks=1 fragment column

  // per-thread staging source bases (pre-swizzled global column)
  const int r0 = tid >> 3;                                  // 0..63
  const int sk = (((tid & 7) ^ (r0 & 7)) << 3);             // elems, <64
  const short* Ag = A + (size_t)(m0 + r0) * lda + sk;
  const short* Bg = W + (size_t)(n0 + ((r0 >> 5) << 6) + (r0 & 31)) * ldw + sk;
  const int ldsArow = wv << 3;                              // wave-uniform
  const int ldsBrow = ((wv >> 2) << 6) + ((wv << 3) & 31);  // wave-uniform

  short8 a[4][2], b0[2][2], b1[2][2];
  floatx4 acc[8][4] = {};

  // prologue: stage tile 0 into buf0, consumption order A0, B0, B1, A1;
  // then the steady-state tile-boundary guard {vmcnt(4); barrier}.
  STGA(0, 0, 0);
  STGB(65536, 0, 0);
  STGB(65536, 1, 0);
  STGA(0, 1, 0);
  VMC(4); BARR;

  const int NT = K >> 6;
  for (int t = 0; t < NT; ++t) {
    const int cb   = t & 1;
    const int ab   = cb << 15;              // compute A buffer (bytes)
    const int bbuf = 65536 + ab;            // compute B buffer
    const int an   = (cb ^ 1) << 15;        // stage A buffer
    const int bn   = 65536 + an;            // stage B buffer
    const int kk   = (t + 1) << 6;
    const bool st  = (t + 1) < NT;

    // ---- phase 1: quadrant (0,0); reads guarded by prev {vmcnt(4);BARR}
    LDA4(ab, 0);
    LDB2(bbuf, 0, b0);
    if (st) STGA(an, 0, kk);
    BARR; LGKM0; SCHED0;
    MM8(0, 0, b0);
    if (st) { VMC(4); } else { VMC(2); }    // guard ph2's B1(t)
    BARR;

    // ---- phase 2: quadrant (0,1)
    LDB2(bbuf, 1, b1);
    if (st) STGB(bn, 0, kk);
    BARR; LGKM0; SCHED0;
    MM8(0, 1, b1);
    if (st) { VMC(4); } else { VMC(0); }    // guard ph3's A1(t)
    BARR;

    // ---- phase 3: quadrant (1,1)
    LDA4(ab, 1);
    if (st) STGB(bn, 1, kk);
    BARR; LGKM0; SCHED0;
    MM8(1, 1, b1);
    BARR;

    // ---- phase 4: quadrant (1,0); b0 still live, no LDS reads
    if (st) STGA(an, 1, kk);
    BARR; LGKM0; SCHED0;
    MM8(1, 0, b0);
    if (st) { VMC(4); }                     // guard next ph1's A0,B0(t+1)
    BARR;
  }

  // C/D layout: row = quad*4 + r, col = l16  [verified m89/m91]
#pragma unroll
  for (int i = 0; i < 8; ++i) {
#pragma unroll
    for (int j = 0; j < 4; ++j) {
#pragma unroll
      for (int r = 0; r < 4; ++r) {
        int m = m0 + wm + i * 16 + quad * 4 + r;
        int n = n0 + wn + j * 16 + l16;
        float v = acc[i][j][r];
        if (FUSE) v += Dp[n] * b2f(Xr[(size_t)m * ldx + n]);
        st_out(Out + (size_t)m * ldo + n, v);
      }
    }
  }
}

// ---------------------------------------------------------------------------
// C0: fused cast fp32->bf16 for x (16M elems) and the 3 weights (1M each).
// ---------------------------------------------------------------------------
__global__ __launch_bounds__(256) void cast_all(
    const float* __restrict__ x, const float* __restrict__ dt_w,
    const float* __restrict__ B_w, const float* __restrict__ C_w,
    short* __restrict__ xb, short* __restrict__ wcat)
{
  size_t i = ((size_t)blockIdx.x * 256 + threadIdx.x) * 8;
  const size_t NX = (size_t)Mdim * Dd;           // 16,777,216
  const size_t NW = (size_t)Dd * Dd;             // 1,048,576
  if (i < NX) {
    *(short8*)(xb + i) = ld8f(x + i);
  } else {
    size_t j = i - NX;
    const float* src = (j < NW) ? (dt_w + j)
                     : (j < 2 * NW) ? (B_w + (j - NW))
                                    : (C_w + (j - 2 * NW));
    *(short8*)(wcat + j) = ld8f(src);
  }
}

// ---------------------------------------------------------------------------
// S1: single transcendental pass, 1 d per thread (8192 waves).
// Gate math: z = dt_pre + dt_b; e = 2^(z*log2e); L = log2(1+e);
//   sp = ln2*L (softplus); g = 2^(nA*L)  [= exp(sp*nA)]; u = sp*Bp*x.
// ---------------------------------------------------------------------------
__global__ __launch_bounds__(256) void scan_local(
    short* __restrict__ P, const short* __restrict__ xb,
    const float* __restrict__ dt_b, const float* __restrict__ A_log,
    const float* __restrict__ h0,
    float* __restrict__ Pc, float* __restrict__ Hl)
{
  const int b = blockIdx.x >> 7;
  const int c = blockIdx.x & 127;
  const int d = blockIdx.y * 256 + threadIdx.x;

  const float db = dt_b[d];
  const float nA = -EXP2(A_log[d] * LOG2E);

  const size_t mrow = (size_t)b * Sdim + (size_t)c * LCH;
  short* pp = P + mrow * 2048 + d;           // dt slot; +1024 = Bp slot
  const short* px = xb + mrow * 1024 + d;

  float p = 1.f, h = 0.f;
  short dt_c = pp[0], bp_c = pp[1024], xv_c = px[0];
  for (int t = 0; t < LCH; ++t) {
    short dt_n = 0, bp_n = 0, xv_n = 0;
    if (t + 1 < LCH) {                       // prefetch above the serial chain
      dt_n = pp[2048]; bp_n = pp[2048 + 1024]; xv_n = px[1024];
    }
    float z  = b2f(dt_c) + db;
    float e  = EXP2(z * LOG2E);
    float L  = LOG2(1.f + e);
    float sp = LN2 * L;
    float g  = EXP2(nA * L);
    float u  = sp * b2f(bp_c) * b2f(xv_c);
    if (c == 0 && t == 0) u += g * h0[b * Dd + d];
    h = g * h + u;
    p *= g;
    pp[0]    = f2b(h);                       // own addrs: safe in-place
    pp[1024] = f2b(p);
    pp += 2048; px += 1024;
    dt_c = dt_n; bp_c = bp_n; xv_c = xv_n;
  }
  size_t o = ((size_t)b * CCH + c) * Dd + d;
  Pc[o] = p;
  Hl[o] = h;
}

// ---------------------------------------------------------------------------
// S2: sequential carry over 128 chunks; carry-in overwrites Pc.
// 64 blocks x 64 threads; 8-deep register-group prefetch.
// ---------------------------------------------------------------------------
__global__ __launch_bounds__(64) void scan_carry(
    float* __restrict__ Pc, const float* __restrict__ Hl)
{
  const int t = blockIdx.x * 64 + threadIdx.x;   // 0..4095
  const int b = t >> 10;
  const int d = t & 1023;
  const size_t base = (size_t)b * CCH * Dd + d;
  float st = 0.f;
  for (int cg = 0; cg < CCH; cg += 8) {
    float pv[8], hv[8];
#pragma unroll
    for (int j = 0; j < 8; ++j) {
      size_t o = base + (size_t)(cg + j) * Dd;
      pv[j] = Pc[o]; hv[j] = Hl[o];
    }
#pragma unroll
    for (int j = 0; j < 8; ++j) {
      size_t o = base + (size_t)(cg + j) * Dd;
      Pc[o] = st;
      st = pv[j] * st + hv[j];
    }
  }
}

// ---------------------------------------------------------------------------
// S3: chain-free fixup: h(t) = hl(t) + carry * pg(t); h -> gate slot of P.
// ---------------------------------------------------------------------------
__global__ __launch_bounds__(256) void scan_fix(
    short* __restrict__ P, const float* __restrict__ carry)
{
  size_t idx = ((size_t)blockIdx.x * 256 + threadIdx.x) * 4;  // over 16M elems
  const int m  = (int)(idx >> 10);
  const int d0 = (int)(idx & 1023);
  const int b  = m >> 12;
  const int c  = (m & (Sdim - 1)) >> 5;      // s / LCH
  short4v hl4 = *(const short4v*)(P + (size_t)m * 2048 + d0);
  short4v pg4 = *(const short4v*)(P + (size_t)m * 2048 + 1024 + d0);
  floatx4 cv  = *(const floatx4*)(carry + ((size_t)b * CCH + c) * Dd + d0);
  short4v o4;
#pragma unroll
  for (int j = 0; j < 4; j++)
    o4[j] = f2b(b2f(hl4[j]) + cv[j] * b2f(pg4[j]));
  *(short4v*)(P + (size_t)m * 2048 + d0) = o4;
}

// ---------------------------------------------------------------------------
extern "C" void kernel_launch(void* const* d_in, const int* in_sizes, int n_in,
                              void* d_out, int out_size, void* d_ws, size_t ws_size,
                              hipStream_t stream)
{
  const float* x     = (const float*)d_in[0];  // [4,4096,1024] fp32
  const float* h0    = (const float*)d_in[1];  // [4,1024]
  const float* dt_w  = (const float*)d_in[2];  // [1024,1024]
  const float* dt_b  = (const float*)d_in[3];  // [1024]
  const float* A_log = (const float*)d_in[4];  // [1024]
  const float* B_w   = (const float*)d_in[5];  // [1024,1024]
  const float* C_w   = (const float*)d_in[6];  // [1024,1024]
  const float* Dp    = (const float*)d_in[7];  // [1024]
  float* out = (float*)d_out;                  // [4,4096,1024] fp32

  // ws layout (106 MB):
  //   [0,64)    P bf16 [16384][2048]: dt_pre|Bp -> hl|pg -> h|pg
  //   [64,96)   xb bf16 [16384][1024]
  //   [96,102)  wcat bf16 [3072][1024]  (dt_w | B_w | C_w)
  //   [102,104) Pc fp32 [4][128][1024]
  //   [104,106) Hl fp32 [4][128][1024]
  char* ws = (char*)d_ws;
  short* P    = (short*)(ws);
  short* xb   = (short*)(ws + (64ull  << 20));
  short* wcat = (short*)(ws + (96ull  << 20));
  float* Pc   = (float*)(ws + (102ull << 20));
  float* Hl   = (float*)(ws + (104ull << 20));

  // C0: all casts in one launch: (16M + 3M)/8/256 = 9728 blocks
  cast_all<<<9728, 256, 0, stream>>>(x, dt_w, B_w, C_w, xb, wcat);

  // K1: P = x @ [dt_w;B_w]^T  (M=16384, N=2048, K=1024), 256² tiles
  gemm8<short, false><<<dim3(Mdim / 256, 2048 / 256), 512, 0, stream>>>(
      xb, Dd, wcat, Dd, P, 2048, 1024, nullptr, nullptr, 0);

  // S1-S3: chunked scan, transcendentals once, fixup chain-free
  scan_local<<<dim3(Bdim * CCH, Dd / 256), 256, 0, stream>>>(
      P, xb, dt_b, A_log, h0, Pc, Hl);
  scan_carry<<<64, 64, 0, stream>>>(Pc, Hl);
  scan_fix<<<(Mdim * Dd / 4) / 256, 256, 0, stream>>>(P, Pc);

  // K6: out = h @ C_w^T + D*x  (h bf16 in P lda=2048; D*x epilogue from xb)
  gemm8<float, true><<<dim3(Mdim / 256, 1024 / 256), 512, 0, stream>>>(
      P, 2048, wcat + 2 * 1024 * 1024, Dd, out, Dd, 1024, Dp, xb, Dd);
}

// Round 4
// 290.807 us; speedup vs baseline: 1.0268x; 1.0268x over previous
//
#include <hip/hip_runtime.h>
#include <hip/hip_bf16.h>
#include <stdint.h>
#include <stddef.h>

// SimpleStateSpaceModel: B=4, S=4096, D=1024. FP32 in/out; bf16 MFMA inside.
// Pipeline (106 MB of d_ws):
//   C0 cast_all         : x->xb (32MB), {dt_w,B_w,C_w}->wcat (6MB)
//   K1 gemm8<bf16>      : P[m,0:1024]=x@dt_w^T, P[m,1024:2048]=x@B_w^T
//   S1 scan_local       : g,u from (P,xb); in-place P <- [hl(t) | pg(t)]
//   S2 scan_carry       : sequential combine over 128 chunks
//   S3 scan_fix         : h(t) = hl(t) + carry*pg(t)
//   K6 gemm8<f32>       : out = h@C_w^T + D*x (xb epilogue)
// R4: GEMM reverted to the R1 schedule (R3's 2-barrier/LGKM0-drain phases
// regressed: compiler's fine-grained lgkmcnt interleave beats a full drain).
// On top of R1: last K-tile peeled (branch-free 15-tile hot loop) and 2
// K-tiles unrolled per iteration so all four LDS buffer bases are literals
// (no runtime t&1 address math). Waits/barriers/staging order identical to
// R1 steady state. Scan/cast unchanged from R2. K hardcoded 1024 (NT=16).

#define Bdim 4
#define Sdim 4096
#define Dd   1024
#define Mdim (Bdim * Sdim)      // 16384
#define CCH  128                // scan chunks per sequence
#define LCH  (Sdim / CCH)       // 32 steps per chunk

typedef __attribute__((ext_vector_type(8))) short  short8;
typedef __attribute__((ext_vector_type(4))) short  short4v;
typedef __attribute__((ext_vector_type(4))) float  floatx4;

#if __has_builtin(__builtin_amdgcn_exp2f)
#define EXP2(x) __builtin_amdgcn_exp2f(x)
#else
#define EXP2(x) exp2f(x)
#endif
#if __has_builtin(__builtin_amdgcn_logf)
#define LOG2(x) __builtin_amdgcn_logf(x)
#else
#define LOG2(x) __log2f(x)
#endif
#define LOG2E 1.44269504088896f
#define LN2   0.69314718055995f

__device__ __forceinline__ float b2f(short v) {
  unsigned u = ((unsigned)(unsigned short)v) << 16;
  float f; __builtin_memcpy(&f, &u, 4); return f;
}
// HW RNE bf16 convert
__device__ __forceinline__ short f2b(float f) {
  __hip_bfloat16 h = __float2bfloat16(f);
  short s; __builtin_memcpy(&s, &h, 2); return s;
}

__device__ __forceinline__ short8 ld8f(const float* p) {
  floatx4 lo = *(const floatx4*)p;
  floatx4 hi = *(const floatx4*)(p + 4);
  short8 r;
  r[0] = f2b(lo[0]); r[1] = f2b(lo[1]); r[2] = f2b(lo[2]); r[3] = f2b(lo[3]);
  r[4] = f2b(hi[0]); r[5] = f2b(hi[1]); r[6] = f2b(hi[2]); r[7] = f2b(hi[3]);
  return r;
}

__device__ __forceinline__ void st_out(short* p, float v) { *p = f2b(v); }
__device__ __forceinline__ void st_out(float* p, float v) { *p = v; }

// async 16B global->LDS (DMA). lds dest wave-uniform; lane i -> l + i*16. [m97]
__device__ __forceinline__ void cp16(const void* g, void* l) {
  __builtin_amdgcn_global_load_lds(
      (__attribute__((address_space(1))) void*)g,
      (__attribute__((address_space(3))) void*)l, 16, 0, 0);
}

// ---------------------------------------------------------------------------
// gemm8: Out[m,n] = sum_k A[m,k]*W[n,k], A/W bf16, K=1024 (NT=16 K-tiles).
// 256x256 tile, BK=64, 8 waves (2M x 4N), per-wave 128x64 output.
// R1 schedule: per tile 4 phases = C-quadrants (0,0),(0,1),(1,1),(1,0);
// phase = {WBAR(vmcnt4+barrier); ds_read frags; stage next half-tile; MFMA
// (compiler fine-grained lgkmcnt)}. Steady state 6-8 loads in flight; each
// consumed half-tile staged 4 phases earlier. vmcnt never 0 except epilogue.
// ---------------------------------------------------------------------------
#define STGA(bufB, h, kk) do { \
  cp16(Ag + (size_t)((h) * 64) * lda + (kk), \
       smc + (bufB) + ((h) * 64 + ldsArow) * 128); \
  cp16(Ag + (size_t)((h) * 64 + 128) * lda + (kk), \
       smc + (bufB) + ((h) * 64 + 128 + ldsArow) * 128); \
} while (0)

#define STGB(bufB, h, kk) do { \
  cp16(Bg + (size_t)((h) * 32) * ldw + (kk), \
       smc + (bufB) + ((h) * 32 + ldsBrow) * 128); \
  cp16(Bg + (size_t)((h) * 32 + 128) * ldw + (kk), \
       smc + (bufB) + ((h) * 32 + 128 + ldsBrow) * 128); \
} while (0)

#define LDA4(bufB, mh) do { \
  _Pragma("unroll") \
  for (int mf = 0; mf < 4; ++mf) { \
    const char* p_ = smc + (bufB) + (wm + (mh) * 64 + mf * 16 + l16) * 128; \
    a[mf][0] = *(const short8*)(p_ + c0x); \
    a[mf][1] = *(const short8*)(p_ + c1x); \
  } \
} while (0)

#define LDB2(bufB, nh, bb) do { \
  _Pragma("unroll") \
  for (int g = 0; g < 2; ++g) { \
    const char* p_ = smc + (bufB) + (wn + (nh) * 32 + g * 16 + l16) * 128; \
    bb[g][0] = *(const short8*)(p_ + c0x); \
    bb[g][1] = *(const short8*)(p_ + c1x); \
  } \
} while (0)

// 16-MFMA cluster (one C-quadrant over K=64). setprio (T5); trailing
// sched_barrier keeps the cluster ahead of the next raw s_barrier.
#define MM8(mh, nh, bb) do { \
  __builtin_amdgcn_s_setprio(1); \
  _Pragma("unroll") \
  for (int mf = 0; mf < 4; ++mf) { \
    _Pragma("unroll") \
    for (int g = 0; g < 2; ++g) { \
      floatx4 c_ = acc[(mh) * 4 + mf][(nh) * 2 + g]; \
      c_ = __builtin_amdgcn_mfma_f32_16x16x32_bf16(a[mf][0], bb[g][0], c_, 0, 0, 0); \
      c_ = __builtin_amdgcn_mfma_f32_16x16x32_bf16(a[mf][1], bb[g][1], c_, 0, 0, 0); \
      acc[(mh) * 4 + mf][(nh) * 2 + g] = c_; \
    } \
  } \
  __builtin_amdgcn_s_setprio(0); \
  __builtin_amdgcn_sched_barrier(0); \
} while (0)

#define WBAR(n) asm volatile("s_waitcnt vmcnt(" n ")\n\ts_barrier" ::: "memory")
#define BARO()  asm volatile("s_barrier" ::: "memory")

// one full K-tile, all staging unconditional (hot loop only).
// AB/BBUF/AN/BN are compile-time buffer byte-bases; kk compile-time-ish col.
#define KSTEP(AB, BBUF, AN, BN, kk) do { \
  WBAR("4"); \
  LDA4(AB, 0); \
  LDB2(BBUF, 0, b0); \
  STGA(AN, 0, kk); \
  MM8(0, 0, b0); \
  WBAR("4"); \
  LDB2(BBUF, 1, b1); \
  STGB(BN, 0, kk); \
  MM8(0, 1, b1); \
  WBAR("4"); \
  LDA4(AB, 1); \
  STGB(BN, 1, kk); \
  MM8(1, 1, b1); \
  BARO(); \
  STGA(AN, 1, kk); \
  MM8(1, 0, b0); \
} while (0)

template <typename OT, bool FUSE>
__global__ __launch_bounds__(512, 2) void gemm8(
    const short* __restrict__ A, int lda,
    const short* __restrict__ W, int ldw,    // bf16 [N][K] row-major
    OT* __restrict__ Out, int ldo,
    const float* __restrict__ Dp, const short* __restrict__ Xr, int ldx)
{
  __shared__ short smem[65536];   // 128 KiB: Abuf0|Abuf1|Bbuf0|Bbuf1, 32K each
  char* smc = (char*)smem;

  const int tid  = threadIdx.x;
  const int lane = tid & 63, wv = tid >> 6;
  const int quad = lane >> 4, l16 = lane & 15;
  const int wm = (wv & 1) << 7;           // 0 / 128
  const int wn = (wv >> 1) << 6;          // 0,64,128,192
  const int m0 = blockIdx.x << 8;
  const int n0 = blockIdx.y << 8;

  // read-side swizzle: phys col-byte = logical ^ ((row&7)<<4); row&7 == l16&7
  const int sx  = (l16 & 7) << 4;
  const int c0x = (quad << 4) ^ sx;            // ks=0 fragment column
  const int c1x = (64 + (quad << 4)) ^ sx;     // ks=1 fragment column

  // per-thread staging source bases (pre-swizzled global column)
  const int r0 = tid >> 3;                                  // 0..63
  const int sk = (((tid & 7) ^ (r0 & 7)) << 3);             // elems, <64
  const short* Ag = A + (size_t)(m0 + r0) * lda + sk;
  const short* Bg = W + (size_t)(n0 + ((r0 >> 5) << 6) + (r0 & 31)) * ldw + sk;
  const int ldsArow = wv << 3;                              // wave-uniform
  const int ldsBrow = ((wv >> 2) << 6) + ((wv << 3) & 31);  // wave-uniform

  short8 a[4][2], b0[2][2], b1[2][2];
  floatx4 acc[8][4] = {};

  // prologue: stage tile 0 into buf0, consumption order A0, B0, B1, A1
  STGA(0, 0, 0);
  STGB(65536, 0, 0);
  STGB(65536, 1, 0);
  STGA(0, 1, 0);

  // hot loop: tiles 0..13, 2 per iteration, literal buffer bases.
  // even tile: compute {A:0, B:65536}, stage {A:32768, B:98304};
  // odd  tile: compute {A:32768, B:98304}, stage {A:0, B:65536}.
  for (int t = 0; t < 14; t += 2) {
    KSTEP(0,     65536, 32768, 98304, (t + 1) << 6);
    KSTEP(32768, 98304, 0,     65536, (t + 2) << 6);
  }
  // tile 14 (even, still stages tile 15)
  KSTEP(0, 65536, 32768, 98304, 15 << 6);

  // tile 15 epilogue (cb=1, no staging; drain 4 -> 2 -> 0)
  WBAR("4");
  LDA4(32768, 0);
  LDB2(98304, 0, b0);
  MM8(0, 0, b0);
  WBAR("2");
  LDB2(98304, 1, b1);
  MM8(0, 1, b1);
  WBAR("0");
  LDA4(32768, 1);
  MM8(1, 1, b1);
  BARO();
  MM8(1, 0, b0);

  // C/D layout: row = quad*4 + r, col = l16  [verified m89/m91]
#pragma unroll
  for (int i = 0; i < 8; ++i) {
#pragma unroll
    for (int j = 0; j < 4; ++j) {
#pragma unroll
      for (int r = 0; r < 4; ++r) {
        int m = m0 + wm + i * 16 + quad * 4 + r;
        int n = n0 + wn + j * 16 + l16;
        float v = acc[i][j][r];
        if (FUSE) v += Dp[n] * b2f(Xr[(size_t)m * ldx + n]);
        st_out(Out + (size_t)m * ldo + n, v);
      }
    }
  }
}

// ---------------------------------------------------------------------------
// C0: fused cast fp32->bf16 for x (16M elems) and the 3 weights (1M each).
// ---------------------------------------------------------------------------
__global__ __launch_bounds__(256) void cast_all(
    const float* __restrict__ x, const float* __restrict__ dt_w,
    const float* __restrict__ B_w, const float* __restrict__ C_w,
    short* __restrict__ xb, short* __restrict__ wcat)
{
  size_t i = ((size_t)blockIdx.x * 256 + threadIdx.x) * 8;
  const size_t NX = (size_t)Mdim * Dd;           // 16,777,216
  const size_t NW = (size_t)Dd * Dd;             // 1,048,576
  if (i < NX) {
    *(short8*)(xb + i) = ld8f(x + i);
  } else {
    size_t j = i - NX;
    const float* src = (j < NW) ? (dt_w + j)
                     : (j < 2 * NW) ? (B_w + (j - NW))
                                    : (C_w + (j - 2 * NW));
    *(short8*)(wcat + j) = ld8f(src);
  }
}

// ---------------------------------------------------------------------------
// S1: single transcendental pass, 1 d per thread (8192 waves).
// Gate math: z = dt_pre + dt_b; e = 2^(z*log2e); L = log2(1+e);
//   sp = ln2*L (softplus); g = 2^(nA*L)  [= exp(sp*nA)]; u = sp*Bp*x.
// ---------------------------------------------------------------------------
__global__ __launch_bounds__(256) void scan_local(
    short* __restrict__ P, const short* __restrict__ xb,
    const float* __restrict__ dt_b, const float* __restrict__ A_log,
    const float* __restrict__ h0,
    float* __restrict__ Pc, float* __restrict__ Hl)
{
  const int b = blockIdx.x >> 7;
  const int c = blockIdx.x & 127;
  const int d = blockIdx.y * 256 + threadIdx.x;

  const float db = dt_b[d];
  const float nA = -EXP2(A_log[d] * LOG2E);

  const size_t mrow = (size_t)b * Sdim + (size_t)c * LCH;
  short* pp = P + mrow * 2048 + d;           // dt slot; +1024 = Bp slot
  const short* px = xb + mrow * 1024 + d;

  float p = 1.f, h = 0.f;
  short dt_c = pp[0], bp_c = pp[1024], xv_c = px[0];
  for (int t = 0; t < LCH; ++t) {
    short dt_n = 0, bp_n = 0, xv_n = 0;
    if (t + 1 < LCH) {                       // prefetch above the serial chain
      dt_n = pp[2048]; bp_n = pp[2048 + 1024]; xv_n = px[1024];
    }
    float z  = b2f(dt_c) + db;
    float e  = EXP2(z * LOG2E);
    float L  = LOG2(1.f + e);
    float sp = LN2 * L;
    float g  = EXP2(nA * L);
    float u  = sp * b2f(bp_c) * b2f(xv_c);
    if (c == 0 && t == 0) u += g * h0[b * Dd + d];
    h = g * h + u;
    p *= g;
    pp[0]    = f2b(h);                       // own addrs: safe in-place
    pp[1024] = f2b(p);
    pp += 2048; px += 1024;
    dt_c = dt_n; bp_c = bp_n; xv_c = xv_n;
  }
  size_t o = ((size_t)b * CCH + c) * Dd + d;
  Pc[o] = p;
  Hl[o] = h;
}

// ---------------------------------------------------------------------------
// S2: sequential carry over 128 chunks; carry-in overwrites Pc.
// 64 blocks x 64 threads; 8-deep register-group prefetch.
// ---------------------------------------------------------------------------
__global__ __launch_bounds__(64) void scan_carry(
    float* __restrict__ Pc, const float* __restrict__ Hl)
{
  const int t = blockIdx.x * 64 + threadIdx.x;   // 0..4095
  const int b = t >> 10;
  const int d = t & 1023;
  const size_t base = (size_t)b * CCH * Dd + d;
  float st = 0.f;
  for (int cg = 0; cg < CCH; cg += 8) {
    float pv[8], hv[8];
#pragma unroll
    for (int j = 0; j < 8; ++j) {
      size_t o = base + (size_t)(cg + j) * Dd;
      pv[j] = Pc[o]; hv[j] = Hl[o];
    }
#pragma unroll
    for (int j = 0; j < 8; ++j) {
      size_t o = base + (size_t)(cg + j) * Dd;
      Pc[o] = st;
      st = pv[j] * st + hv[j];
    }
  }
}

// ---------------------------------------------------------------------------
// S3: chain-free fixup: h(t) = hl(t) + carry * pg(t); h -> gate slot of P.
// ---------------------------------------------------------------------------
__global__ __launch_bounds__(256) void scan_fix(
    short* __restrict__ P, const float* __restrict__ carry)
{
  size_t idx = ((size_t)blockIdx.x * 256 + threadIdx.x) * 4;  // over 16M elems
  const int m  = (int)(idx >> 10);
  const int d0 = (int)(idx & 1023);
  const int b  = m >> 12;
  const int c  = (m & (Sdim - 1)) >> 5;      // s / LCH
  short4v hl4 = *(const short4v*)(P + (size_t)m * 2048 + d0);
  short4v pg4 = *(const short4v*)(P + (size_t)m * 2048 + 1024 + d0);
  floatx4 cv  = *(const floatx4*)(carry + ((size_t)b * CCH + c) * Dd + d0);
  short4v o4;
#pragma unroll
  for (int j = 0; j < 4; j++)
    o4[j] = f2b(b2f(hl4[j]) + cv[j] * b2f(pg4[j]));
  *(short4v*)(P + (size_t)m * 2048 + d0) = o4;
}

// ---------------------------------------------------------------------------
extern "C" void kernel_launch(void* const* d_in, const int* in_sizes, int n_in,
                              void* d_out, int out_size, void* d_ws, size_t ws_size,
                              hipStream_t stream)
{
  const float* x     = (const float*)d_in[0];  // [4,4096,1024] fp32
  const float* h0    = (const float*)d_in[1];  // [4,1024]
  const float* dt_w  = (const float*)d_in[2];  // [1024,1024]
  const float* dt_b  = (const float*)d_in[3];  // [1024]
  const float* A_log = (const float*)d_in[4];  // [1024]
  const float* B_w   = (const float*)d_in[5];  // [1024,1024]
  const float* C_w   = (const float*)d_in[6];  // [1024,1024]
  const float* Dp    = (const float*)d_in[7];  // [1024]
  float* out = (float*)d_out;                  // [4,4096,1024] fp32

  // ws layout (106 MB):
  //   [0,64)    P bf16 [16384][2048]: dt_pre|Bp -> hl|pg -> h|pg
  //   [64,96)   xb bf16 [16384][1024]
  //   [96,102)  wcat bf16 [3072][1024]  (dt_w | B_w | C_w)
  //   [102,104) Pc fp32 [4][128][1024]
  //   [104,106) Hl fp32 [4][128][1024]
  char* ws = (char*)d_ws;
  short* P    = (short*)(ws);
  short* xb   = (short*)(ws + (64ull  << 20));
  short* wcat = (short*)(ws + (96ull  << 20));
  float* Pc   = (float*)(ws + (102ull << 20));
  float* Hl   = (float*)(ws + (104ull << 20));

  // C0: all casts in one launch: (16M + 3M)/8/256 = 9728 blocks
  cast_all<<<9728, 256, 0, stream>>>(x, dt_w, B_w, C_w, xb, wcat);

  // K1: P = x @ [dt_w;B_w]^T  (M=16384, N=2048, K=1024), 256² tiles
  gemm8<short, false><<<dim3(Mdim / 256, 2048 / 256), 512, 0, stream>>>(
      xb, Dd, wcat, Dd, P, 2048, nullptr, nullptr, 0);

  // S1-S3: chunked scan, transcendentals once, fixup chain-free
  scan_local<<<dim3(Bdim * CCH, Dd / 256), 256, 0, stream>>>(
      P, xb, dt_b, A_log, h0, Pc, Hl);
  scan_carry<<<64, 64, 0, stream>>>(Pc, Hl);
  scan_fix<<<(Mdim * Dd / 4) / 256, 256, 0, stream>>>(P, Pc);

  // K6: out = h @ C_w^T + D*x  (h bf16 in P lda=2048; D*x epilogue from xb)
  gemm8<float, true><<<dim3(Mdim / 256, 1024 / 256), 512, 0, stream>>>(
      P, 2048, wcat + 2 * 1024 * 1024, Dd, out, Dd, Dp, xb, Dd);
}